// Round 5
// baseline (268.989 us; speedup 1.0000x reference)
//
#include <hip/hip_runtime.h>

// RelationLayer, round 17.
// R16: pair stuck ~129us across 3 structures (MfmaUtil 12, Occ 22% ~= 1
// resident block/CU; likely unified VGPR+AGPR pressure beyond reported
// VGPR_Count). Pair FROZEN this round. Attack the other 138us:
//  * conv: 192 blocks on 256 CUs, win3 blocks 3x win1 work (straggler).
//    -> win3 re-tiled to 32-row m-tiles (128 blocks, per-chunk work halved)
//       + win1 128 blocks + wsplit absorbed (96 blocks on idle CUs) = 352.
//  * ab: wsplit removed; 16-row x 64-col tiles -> 512 blocks = 2/CU,
//    K staged 6 x 64.
// Predicted: conv ~45->28, ab ~30->17, total 268 -> ~225.

#define BB 32
#define CCH 384

__device__ __forceinline__ float leaky(float x) { return fmaxf(x, 0.1f * x); }

typedef _Float16 f16x8 __attribute__((ext_vector_type(8)));
typedef float f32x4 __attribute__((ext_vector_type(4)));

union F8 { uint4 q; f16x8 h; };
union H2 { _Float16 f[2]; uint32_t u; };

__device__ __forceinline__ void split2(float d0, float d1,
                                       uint32_t& hw, uint32_t& lw) {
  H2 h, l;
  h.f[0] = (_Float16)d0; h.f[1] = (_Float16)d1;
  l.f[0] = (_Float16)((d0 - (float)h.f[0]) * 2048.0f);
  l.f[1] = (_Float16)((d1 - (float)h.f[1]) * 2048.0f);
  hw = h.u; lw = l.u;
}

// ---------------------------------------------------------------- conv ------
// grid 352:
//   bx 0..127  : win1, 64-row x 64-ch tiles (nb=bx&3, mb=bx>>2), K=512
//   bx 128..255: win3, 32-row x 64-ch tiles (nb3=t&1, mb3=t>>1), K=1536
//   bx 256..351: wsplit for w1..w3 (fills CUs idle during conv)
__global__ __launch_bounds__(256) void conv_kernel(
    const float* __restrict__ x, const float* __restrict__ mask,
    const float* __restrict__ cw0, const float* __restrict__ cw1,
    const float* __restrict__ w1, const float* __restrict__ w2,
    const float* __restrict__ w3,
    float* __restrict__ yG, float* __restrict__ Ssum, float* __restrict__ Ssq,
    uint32_t* __restrict__ wpk)
{
  int bx = blockIdx.x;
  int tid = threadIdx.x;
  if (bx >= 256) {                        // ---- wsplit (was in ab)
    int e = (bx - 256) * 256 + tid;       // 0..24575 (L, k2, n)
    int L = e >> 13;
    int r = e & 8191;
    int k2 = r >> 7, n = r & 127;
    int k = k2 * 2;
    const float* w = (L == 0) ? w1 : (L == 1) ? w2 : w3;
    uint32_t hw, lw;
    split2(w[k * 128 + n], w[(k + 1) * 128 + n], hw, lw);
    wpk[L * 8192 + n * 64 + k2] = hw;
    wpk[24576 + L * 8192 + n * 64 + k2] = lw;
    return;
  }

  __shared__ uint32_t Ah[64 * 68], Al[64 * 68];
  __shared__ uint32_t Bh[64 * 68], Bl[64 * 68];

  int wid = __builtin_amdgcn_readfirstlane(tid >> 6);
  int lane = tid & 63;
  int m16 = lane & 15, q = lane >> 4;

  if (bx < 128) {
    // ================= win1: 64-row tiles, K=512, waves 2m x 2n ============
    int nb = bx & 3, mb = bx >> 2;
    int n0 = nb * 64;
    int row0 = mb * 64;
    const float* wbase = cw0 + n0 * 512;
    int wm = wid & 1, wn2 = wid >> 1;

    f32x4 hi[2][2], cr[2][2];
#pragma unroll
    for (int a = 0; a < 2; ++a)
#pragma unroll
      for (int b = 0; b < 2; ++b) {
        hi[a][b] = (f32x4){0.f, 0.f, 0.f, 0.f};
        cr[a][b] = (f32x4){0.f, 0.f, 0.f, 0.f};
      }

#pragma unroll 1
    for (int ch = 0; ch < 4; ++ch) {
      int kg0 = ch * 128;
      __syncthreads();
#pragma unroll 1
      for (int it = 0; it < 4; ++it) {
        int idx = it * 256 + tid;
        int r = idx >> 4;                  // 0..63
        int k8 = (idx & 15) * 8;
        float d[8];
        int rowg = row0 + r;
        {
          float mv = mask[rowg];
          const float* xp = x + rowg * 512 + kg0 + k8;
          float4 a0 = *(const float4*)xp;
          float4 a1 = *(const float4*)(xp + 4);
          d[0] = a0.x * mv; d[1] = a0.y * mv; d[2] = a0.z * mv; d[3] = a0.w * mv;
          d[4] = a1.x * mv; d[5] = a1.y * mv; d[6] = a1.z * mv; d[7] = a1.w * mv;
        }
        uint4 hq, lq;
        split2(d[0], d[1], hq.x, lq.x);
        split2(d[2], d[3], hq.y, lq.y);
        split2(d[4], d[5], hq.z, lq.z);
        split2(d[6], d[7], hq.w, lq.w);
        *(uint4*)&Ah[r * 68 + k8 / 2] = hq;
        *(uint4*)&Al[r * 68 + k8 / 2] = lq;
        const float* wp = wbase + r * 512 + kg0 + k8;
        float4 b0v = *(const float4*)wp;
        float4 b1v = *(const float4*)(wp + 4);
        split2(b0v.x, b0v.y, hq.x, lq.x);
        split2(b0v.z, b0v.w, hq.y, lq.y);
        split2(b1v.x, b1v.y, hq.z, lq.z);
        split2(b1v.z, b1v.w, hq.w, lq.w);
        *(uint4*)&Bh[r * 68 + k8 / 2] = hq;
        *(uint4*)&Bl[r * 68 + k8 / 2] = lq;
      }
      __syncthreads();
#pragma unroll
      for (int ks = 0; ks < 4; ++ks) {
        int koff = ks * 16 + q * 4;
        F8 bh[2], bl[2];
#pragma unroll
        for (int nt = 0; nt < 2; ++nt) {
          int br = wn2 * 32 + nt * 16 + m16;
          bh[nt].q = *(const uint4*)&Bh[br * 68 + koff];
          bl[nt].q = *(const uint4*)&Bl[br * 68 + koff];
        }
#pragma unroll
        for (int mt = 0; mt < 2; ++mt) {
          int ar = wm * 32 + mt * 16 + m16;
          F8 ah, al;
          ah.q = *(const uint4*)&Ah[ar * 68 + koff];
          al.q = *(const uint4*)&Al[ar * 68 + koff];
#pragma unroll
          for (int nt = 0; nt < 2; ++nt) {
            hi[mt][nt] = __builtin_amdgcn_mfma_f32_16x16x32_f16(
                ah.h, bh[nt].h, hi[mt][nt], 0, 0, 0);
            cr[mt][nt] = __builtin_amdgcn_mfma_f32_16x16x32_f16(
                ah.h, bl[nt].h, cr[mt][nt], 0, 0, 0);
            cr[mt][nt] = __builtin_amdgcn_mfma_f32_16x16x32_f16(
                al.h, bh[nt].h, cr[mt][nt], 0, 0, 0);
          }
        }
      }
    }

    float y[2][2][4];
#pragma unroll
    for (int mt = 0; mt < 2; ++mt)
#pragma unroll
      for (int nt = 0; nt < 2; ++nt)
#pragma unroll
        for (int rg = 0; rg < 4; ++rg)
          y[mt][nt][rg] = hi[mt][nt][rg] + cr[mt][nt][rg] * (1.0f / 2048.0f);

#pragma unroll
    for (int nt = 0; nt < 2; ++nt) {
      float s = 0.f, s2 = 0.f;
#pragma unroll
      for (int mt = 0; mt < 2; ++mt)
#pragma unroll
        for (int rg = 0; rg < 4; ++rg) {
          float v = y[mt][nt][rg];
          s += v; s2 += v * v;
        }
      s  += __shfl_xor(s, 16, 64);  s  += __shfl_xor(s, 32, 64);
      s2 += __shfl_xor(s2, 16, 64); s2 += __shfl_xor(s2, 32, 64);
      if (lane < 16) {
        int c = n0 + wn2 * 32 + nt * 16 + m16;
        atomicAdd(&Ssum[c], s);
        atomicAdd(&Ssq[c], s2);
      }
    }

    __syncthreads();
    float* Yl = (float*)Ah;                // 64 x 68 floats
#pragma unroll
    for (int mt = 0; mt < 2; ++mt)
#pragma unroll
      for (int nt = 0; nt < 2; ++nt)
#pragma unroll
        for (int rg = 0; rg < 4; ++rg)
          Yl[(wn2 * 32 + nt * 16 + m16) * 68 + wm * 32 + mt * 16 + q * 4 + rg] =
              y[mt][nt][rg];
    __syncthreads();
    {
      int c = tid >> 2, seg = (tid & 3) * 16;
#pragma unroll
      for (int j = 0; j < 16; j += 4)
        *(float4*)&yG[(n0 + c) * 2048 + row0 + seg + j] =
            *(const float4*)&Yl[c * 68 + seg + j];
    }
    return;
  }

  // ================= win3: 32-row tiles, K=1536, waves 1m x 4n ============
  {
    int t = bx - 128;
    int nb3 = t & 1, mb3 = t >> 1;
    int n0 = 256 + nb3 * 64;               // global channel base
    int row0 = mb3 * 32;
    const float* wbase = cw1 + (n0 - 256) * 1536;

    f32x4 hi3[2], cr3[2];
#pragma unroll
    for (int mt = 0; mt < 2; ++mt) {
      hi3[mt] = (f32x4){0.f, 0.f, 0.f, 0.f};
      cr3[mt] = (f32x4){0.f, 0.f, 0.f, 0.f};
    }

#pragma unroll 1
    for (int ch = 0; ch < 12; ++ch) {
      int kg0 = ch * 128;
      int tap = kg0 >> 9;                  // 0..2
      int d0 = kg0 & 511;
      int shift = (tap - 1) * 32;
      __syncthreads();
#pragma unroll 1
      for (int it = 0; it < 6; ++it) {
        int idx = it * 256 + tid;          // 0..1535
        if (idx < 512) {                   // A: 32 rows x 16 k8
          int r = idx >> 4;                // 0..31
          int k8 = (idx & 15) * 8;
          float d[8];
          int rowg = row0 + r + shift;
          if ((unsigned)rowg < 2048u) {
            float mv = mask[rowg];
            const float* xp = x + rowg * 512 + d0 + k8;
            float4 a0 = *(const float4*)xp;
            float4 a1 = *(const float4*)(xp + 4);
            d[0] = a0.x * mv; d[1] = a0.y * mv; d[2] = a0.z * mv; d[3] = a0.w * mv;
            d[4] = a1.x * mv; d[5] = a1.y * mv; d[6] = a1.z * mv; d[7] = a1.w * mv;
          } else {
#pragma unroll
            for (int t2 = 0; t2 < 8; ++t2) d[t2] = 0.f;
          }
          uint4 hq, lq;
          split2(d[0], d[1], hq.x, lq.x);
          split2(d[2], d[3], hq.y, lq.y);
          split2(d[4], d[5], hq.z, lq.z);
          split2(d[6], d[7], hq.w, lq.w);
          *(uint4*)&Ah[r * 68 + k8 / 2] = hq;
          *(uint4*)&Al[r * 68 + k8 / 2] = lq;
        } else {                           // B: 64 ch x 16 k8
          int idx2 = idx - 512;
          int r = idx2 >> 4;               // 0..63
          int k8 = (idx2 & 15) * 8;
          const float* wp = wbase + r * 1536 + kg0 + k8;
          float4 b0v = *(const float4*)wp;
          float4 b1v = *(const float4*)(wp + 4);
          uint4 hq, lq;
          split2(b0v.x, b0v.y, hq.x, lq.x);
          split2(b0v.z, b0v.w, hq.y, lq.y);
          split2(b1v.x, b1v.y, hq.z, lq.z);
          split2(b1v.z, b1v.w, hq.w, lq.w);
          *(uint4*)&Bh[r * 68 + k8 / 2] = hq;
          *(uint4*)&Bl[r * 68 + k8 / 2] = lq;
        }
      }
      __syncthreads();
#pragma unroll
      for (int ks = 0; ks < 4; ++ks) {
        int koff = ks * 16 + q * 4;
        F8 bh, bl;
        int br = wid * 16 + m16;
        bh.q = *(const uint4*)&Bh[br * 68 + koff];
        bl.q = *(const uint4*)&Bl[br * 68 + koff];
#pragma unroll
        for (int mt = 0; mt < 2; ++mt) {
          int ar = mt * 16 + m16;
          F8 ah, al;
          ah.q = *(const uint4*)&Ah[ar * 68 + koff];
          al.q = *(const uint4*)&Al[ar * 68 + koff];
          hi3[mt] = __builtin_amdgcn_mfma_f32_16x16x32_f16(
              ah.h, bh.h, hi3[mt], 0, 0, 0);
          cr3[mt] = __builtin_amdgcn_mfma_f32_16x16x32_f16(
              ah.h, bl.h, cr3[mt], 0, 0, 0);
          cr3[mt] = __builtin_amdgcn_mfma_f32_16x16x32_f16(
              al.h, bh.h, cr3[mt], 0, 0, 0);
        }
      }
    }

    float y3[2][4];
#pragma unroll
    for (int mt = 0; mt < 2; ++mt)
#pragma unroll
      for (int rg = 0; rg < 4; ++rg)
        y3[mt][rg] = hi3[mt][rg] + cr3[mt][rg] * (1.0f / 2048.0f);

    // BN stats: wave owns 16 cols x 32 rows
    {
      float s = 0.f, s2 = 0.f;
#pragma unroll
      for (int mt = 0; mt < 2; ++mt)
#pragma unroll
        for (int rg = 0; rg < 4; ++rg) {
          float v = y3[mt][rg];
          s += v; s2 += v * v;
        }
      s  += __shfl_xor(s, 16, 64);  s  += __shfl_xor(s, 32, 64);
      s2 += __shfl_xor(s2, 16, 64); s2 += __shfl_xor(s2, 32, 64);
      if (lane < 16) {
        int c = n0 + wid * 16 + m16;
        atomicAdd(&Ssum[c], s);
        atomicAdd(&Ssq[c], s2);
      }
    }

    __syncthreads();
    float* Yl = (float*)Ah;                // 64 cols x 34 floats
#pragma unroll
    for (int mt = 0; mt < 2; ++mt)
#pragma unroll
      for (int rg = 0; rg < 4; ++rg)
        Yl[(wid * 16 + m16) * 34 + mt * 16 + q * 4 + rg] = y3[mt][rg];
    __syncthreads();
    {
      int c = tid >> 2, seg = (tid & 3) * 8;
#pragma unroll
      for (int j = 0; j < 8; j += 4)
        *(float4*)&yG[(n0 + c) * 2048 + row0 + seg + j] =
            *(const float4*)&Yl[c * 34 + seg + j];
    }
  }
}

// ------------------------------------------------------------------ ab ------
// grid 512: 16-row x 64-col tiles (rt=bx>>2, ct=bx&3), K staged 6 x 64.
__global__ __launch_bounds__(256) void ab_kernel(
    const float* __restrict__ yG, const float* __restrict__ Ssum,
    const float* __restrict__ Ssq,
    const float* __restrict__ g0, const float* __restrict__ be0,
    const float* __restrict__ g1, const float* __restrict__ be1,
    const float* __restrict__ mask, const float* __restrict__ w0,
    float* __restrict__ a_arr, float* __restrict__ bb_arr)
{
  int bx = blockIdx.x;
  int tid = threadIdx.x;
  __shared__ float As[64 * 20];
  __shared__ float Ws[64 * 68];
  __shared__ float scs[384], shs[384];
  for (int c = tid; c < 384; c += 256) {
    float Sv = Ssum[c], S2v = Ssq[c];
    float mean = Sv * (1.f / 2048.f);
    float var  = S2v * (1.f / 2048.f) - mean * mean;
    float g  = (c < 256) ? g0[c] : g1[c - 256];
    float be = (c < 256) ? be0[c] : be1[c - 256];
    float sc = g / sqrtf(var + 1e-5f);
    scs[c] = sc;
    shs[c] = be - mean * sc;
  }
  __syncthreads();

  int rt = bx >> 2, ct = bx & 3;
  int row0 = rt * 16, n0 = ct * 64;
  int cth = tid >> 2;                    // 0..63: staged channel
  int srr4 = (tid & 3) * 4;              // 0..12: staged row group
  int wn16 = (tid & 3) * 16;             // staged weight col group
  int r4 = (tid >> 6) * 4;               // 0..12: sweep row group
  int n1 = tid & 63;                     // sweep col
  const float* wbase = (n0 < 128) ? (w0 + n0) : (w0 + CCH * 128 + (n0 - 128));
  float4 mv = *(const float4*)(mask + row0 + srr4);

  float acc[4] = {0.f, 0.f, 0.f, 0.f};
#pragma unroll 1
  for (int c0 = 0; c0 < 384; c0 += 64) {
    int c = c0 + cth;
    float4 yv = *(const float4*)(yG + c * 2048 + row0 + srr4);
    float sc = scs[c], sh = shs[c];
    float4 wv0 = *(const float4*)(wbase + c * 128 + wn16);
    float4 wv1 = *(const float4*)(wbase + c * 128 + wn16 + 4);
    float4 wv2 = *(const float4*)(wbase + c * 128 + wn16 + 8);
    float4 wv3 = *(const float4*)(wbase + c * 128 + wn16 + 12);
    __syncthreads();
    float4 hv;
    hv.x = leaky(fmaf(yv.x, sc, sh)) * mv.x;
    hv.y = leaky(fmaf(yv.y, sc, sh)) * mv.y;
    hv.z = leaky(fmaf(yv.z, sc, sh)) * mv.z;
    hv.w = leaky(fmaf(yv.w, sc, sh)) * mv.w;
    *(float4*)&As[cth * 20 + srr4] = hv;
    *(float4*)&Ws[cth * 68 + wn16]      = wv0;
    *(float4*)&Ws[cth * 68 + wn16 + 4]  = wv1;
    *(float4*)&Ws[cth * 68 + wn16 + 8]  = wv2;
    *(float4*)&Ws[cth * 68 + wn16 + 12] = wv3;
    __syncthreads();
#pragma unroll 16
    for (int cc = 0; cc < 64; ++cc) {
      float4 a = *(const float4*)&As[cc * 20 + r4];
      float w  = Ws[cc * 68 + n1];
      acc[0] = fmaf(a.x, w, acc[0]);
      acc[1] = fmaf(a.y, w, acc[1]);
      acc[2] = fmaf(a.z, w, acc[2]);
      acc[3] = fmaf(a.w, w, acc[3]);
    }
  }
  float* dst; int nd;
  if (n0 < 128) { dst = a_arr; nd = n0; } else { dst = bb_arr; nd = n0 - 128; }
#pragma unroll
  for (int ri = 0; ri < 4; ++ri)
    dst[(row0 + r4 + ri) * 128 + nd + n1] = acc[ri];
}

// ---------------------------------------------------------------- pair ------
// R16 verbatim (frozen this round): grid (64,32), 8 waves 1m x 8n,
// ks-double-buffered weights with cross-layer hoist, launch_bounds(512,3).
__global__ __launch_bounds__(512, 3) void pair_kernel(
    const float* __restrict__ a_arr, const float* __restrict__ bb_arr,
    const float* __restrict__ b0, const uint32_t* __restrict__ wpk,
    const float* __restrict__ b1, const float* __restrict__ b2,
    const float* __restrict__ b3,
    const float* __restrict__ w4, const float* __restrict__ b4,
    const float* __restrict__ w5, const float* __restrict__ b5,
    const float* __restrict__ mask, float* __restrict__ out)
{
  __shared__ uint32_t Ahs[64 * 68];
  __shared__ uint32_t Als[64 * 68];
  int i = blockIdx.x, b = blockIdx.y;
  int tid = threadIdx.x;
  int browp = i * BB + b;

  int wid = __builtin_amdgcn_readfirstlane(tid >> 6);
  int lane = tid & 63;
  int m16 = lane & 15, q = lane >> 4;
  int wn16 = wid * 16;
  int wrow = wn16 + m16;

  F8 Wh, Wl, Whn, Wln;
  {
    const uint32_t* W0h = wpk + wrow * 64 + q * 4;
    const uint32_t* W0l = wpk + 24576 + wrow * 64 + q * 4;
    Wh.q = *(const uint4*)W0h;
    Wl.q = *(const uint4*)W0l;
  }

  {
    int k8 = (tid & 15) * 8;
    const float* ap = a_arr + browp * 128 + k8;
    const float* zp = b0 + k8;
    float az[8];
#pragma unroll
    for (int t = 0; t < 8; t += 4) {
      float4 av = *(const float4*)(ap + t);
      float4 zv = *(const float4*)(zp + t);
      az[t + 0] = av.x + zv.x; az[t + 1] = av.y + zv.y;
      az[t + 2] = av.z + zv.z; az[t + 3] = av.w + zv.w;
    }
#pragma unroll
    for (int it = 0; it < 2; ++it) {
      int r = (it * 512 + tid) >> 4;
      const float* bbp = bb_arr + (r * BB + b) * 128 + k8;
      float d[8];
#pragma unroll
      for (int t = 0; t < 8; t += 4) {
        float4 bv = *(const float4*)(bbp + t);
        d[t + 0] = leaky(az[t + 0] + bv.x);
        d[t + 1] = leaky(az[t + 1] + bv.y);
        d[t + 2] = leaky(az[t + 2] + bv.z);
        d[t + 3] = leaky(az[t + 3] + bv.w);
      }
      uint4 hq, lq;
      split2(d[0], d[1], hq.x, lq.x);
      split2(d[2], d[3], hq.y, lq.y);
      split2(d[4], d[5], hq.z, lq.z);
      split2(d[6], d[7], hq.w, lq.w);
      *(uint4*)&Ahs[r * 68 + k8 / 2] = hq;
      *(uint4*)&Als[r * 68 + k8 / 2] = lq;
    }
  }
  __syncthreads();

  f32x4 hi[4], cr[4];

#pragma unroll 1
  for (int L = 0; L < 3; ++L) {
    const uint32_t* WhL = wpk + L * 8192;
    const uint32_t* WlL = wpk + 24576 + L * 8192;
    const float* Bv = (L == 0) ? b1 : (L == 1) ? b2 : b3;
#pragma unroll
    for (int mt = 0; mt < 4; ++mt) {
      hi[mt] = (f32x4){0.f, 0.f, 0.f, 0.f};
      cr[mt] = (f32x4){0.f, 0.f, 0.f, 0.f};
    }

#pragma unroll
    for (int ks = 0; ks < 4; ++ks) {
      int koff = ks * 16 + q * 4;
      if (ks < 3) {
        Whn.q = *(const uint4*)(WhL + wrow * 64 + koff + 16);
        Wln.q = *(const uint4*)(WlL + wrow * 64 + koff + 16);
      } else if (L < 2) {
        Whn.q = *(const uint4*)(WhL + 8192 + wrow * 64 + q * 4);
        Wln.q = *(const uint4*)(WlL + 8192 + wrow * 64 + q * 4);
      }
#pragma unroll
      for (int mt = 0; mt < 4; ++mt) {
        int arow = mt * 16 + m16;
        F8 Ah, Al;
        Ah.q = *(const uint4*)&Ahs[arow * 68 + koff];
        Al.q = *(const uint4*)&Als[arow * 68 + koff];
        hi[mt] = __builtin_amdgcn_mfma_f32_16x16x32_f16(
            Ah.h, Wh.h, hi[mt], 0, 0, 0);
        cr[mt] = __builtin_amdgcn_mfma_f32_16x16x32_f16(
            Ah.h, Wl.h, cr[mt], 0, 0, 0);
        cr[mt] = __builtin_amdgcn_mfma_f32_16x16x32_f16(
            Al.h, Wh.h, cr[mt], 0, 0, 0);
      }
      Wh = Whn; Wl = Wln;
    }

    float bias = Bv[wrow];

    if (L < 2) {
      __syncthreads();
      int par = lane & 1;
      int colw = (wn16 + (m16 & ~1)) >> 1;
#pragma unroll
      for (int mt = 0; mt < 4; ++mt) {
#pragma unroll
        for (int rg = 0; rg < 4; ++rg) {
          float d = leaky(hi[mt][rg] + cr[mt][rg] * (1.0f / 2048.0f) + bias);
          float dn = __shfl_xor(d, 1, 64);
          float de = par ? dn : d;
          float do_ = par ? d : dn;
          uint32_t hw, lw;
          split2(de, do_, hw, lw);
          int row = mt * 16 + q * 4 + rg;
          if (par) Als[row * 68 + colw] = lw;
          else     Ahs[row * 68 + colw] = hw;
        }
      }
      __syncthreads();
    } else {
      float s = 0.f;
#pragma unroll
      for (int mt = 0; mt < 4; ++mt)
#pragma unroll
        for (int rg = 0; rg < 4; ++rg)
          s += leaky(hi[mt][rg] + cr[mt][rg] * (1.0f / 2048.0f) + bias);
      s += __shfl_xor(s, 16, 64);
      s += __shfl_xor(s, 32, 64);
      float mfac = (1.0f / 64.0f) * mask[browp];
      __syncthreads();
      float* scratch = (float*)Ahs;
      float* Pm = scratch;
      float* Tp = scratch + 128;
      float* T4 = scratch + 640;
      if (lane < 16) Pm[wrow] = s * mfac;
      __syncthreads();
      {
        int k = tid & 127, chh = tid >> 7;
        const float* w4c = w4 + (chh * 32) * 128 + k;
        const float* pc = Pm + chh * 32;
        float t = 0.f;
#pragma unroll 8
        for (int c0 = 0; c0 < 32; c0 += 4) {
          float4 pv = *(const float4*)&pc[c0];
          t = fmaf(pv.x, w4c[(c0 + 0) * 128], t);
          t = fmaf(pv.y, w4c[(c0 + 1) * 128], t);
          t = fmaf(pv.z, w4c[(c0 + 2) * 128], t);
          t = fmaf(pv.w, w4c[(c0 + 3) * 128], t);
        }
        Tp[chh * 128 + k] = t;
      }
      __syncthreads();
      if (tid < 128)
        T4[tid] = leaky(Tp[tid] + Tp[128 + tid] + Tp[256 + tid] +
                        Tp[384 + tid] + b4[tid]);
      __syncthreads();
      {
        float o = b5[tid];
#pragma unroll 4
        for (int c0 = 0; c0 < 128; c0 += 4) {
          float4 tv = *(const float4*)&T4[c0];
          o = fmaf(tv.x, w5[(c0 + 0) * 512 + tid], o);
          o = fmaf(tv.y, w5[(c0 + 1) * 512 + tid], o);
          o = fmaf(tv.z, w5[(c0 + 2) * 512 + tid], o);
          o = fmaf(tv.w, w5[(c0 + 3) * 512 + tid], o);
        }
        out[browp * 512 + tid] = leaky(o) * mask[browp];
      }
    }
  }
}

// -------------------------------------------------------------- launch ------
extern "C" void kernel_launch(void* const* d_in, const int* in_sizes, int n_in,
                              void* d_out, int out_size, void* d_ws, size_t ws_size,
                              hipStream_t stream) {
  const float* x    = (const float*)d_in[0];
  const float* mask = (const float*)d_in[1];
  const float* cw0  = (const float*)d_in[2];
  // d_in[3] conv_b0: cancels in BN
  const float* g0   = (const float*)d_in[4];
  const float* be0  = (const float*)d_in[5];
  const float* cw1  = (const float*)d_in[6];
  // d_in[7] conv_b1: cancels in BN
  const float* g1   = (const float*)d_in[8];
  const float* be1  = (const float*)d_in[9];
  const float* w0   = (const float*)d_in[10];
  const float* b0   = (const float*)d_in[11];
  const float* w1   = (const float*)d_in[12];
  const float* b1   = (const float*)d_in[13];
  const float* w2   = (const float*)d_in[14];
  const float* b2   = (const float*)d_in[15];
  const float* w3   = (const float*)d_in[16];
  const float* b3   = (const float*)d_in[17];
  const float* w4   = (const float*)d_in[18];
  const float* b4   = (const float*)d_in[19];
  const float* w5   = (const float*)d_in[20];
  const float* b5   = (const float*)d_in[21];

  float* ws     = (float*)d_ws;
  float* Ssum   = ws;                         // 384
  float* Ssq    = ws + 384;                   // 384
  float* yG     = ws + 768;                   // 384*2048 = 786432
  uint32_t* wpk = (uint32_t*)(ws + 787200);   // 49152
  float* a_arr  = ws + 836352;                // 2048*128
  float* bb_arr = ws + 1098496;               // 2048*128
  float* outp   = (float*)d_out;

  hipMemsetAsync(Ssum, 0, 768 * sizeof(float), stream);
  conv_kernel<<<352, 256, 0, stream>>>(x, mask, cw0, cw1, w1, w2, w3,
                                       yG, Ssum, Ssq, wpk);
  ab_kernel<<<512, 256, 0, stream>>>(yG, Ssum, Ssq, g0, be0, g1, be1,
                                     mask, w0, a_arr, bb_arr);
  dim3 g5(64, 32);
  pair_kernel<<<g5, 512, 0, stream>>>(a_arr, bb_arr, b0, wpk, b1, b2, b3,
                                      w4, b4, w5, b5, mask, outp);
}

// Round 6
// 266.048 us; speedup vs baseline: 1.0111x; 1.0111x over previous
//
#include <hip/hip_runtime.h>

// RelationLayer, round 18.
// R17: conv/ab restructure changed total by 0.1us -- non-pair ~142us is
// INVARIANT across 4 configs; cannot attack it blind (rows not in top-5).
// Pair: 127us = 8 serial blocks/CU x ~16us phase-chain, ~1 block resident
// (Occ 22%), epilogue re-reads all of w5 (256KB) + w4 per block.
// R18: pair -> grid (64,4) = 1 block/CU, 8 b-iterations each:
//  * A-staging double-buffered (2x34.8KB LDS): loads for b+1 issue at t
//    start (hide under L0 MFMA), split2+write lands after L0 rewrite.
//  * epilogue stripped: pair stores p (128/row) to p_arr (reuses dead yG);
//    new out_kernel (256 blk x 256 thr, 8 rows) does p@w4 -> @w5 with
//    w5 staged per block (512MB -> 64MB L2 traffic).
//  * weight ks-double-buffer kept, wraps across t (L1-hot after t0).
// Predicted: pair 127->40-60us, out ~5us, total 269 -> ~185-210.
// If total >=230: non-pair 142us is real; conv/ab surface in top-5 next.

#define BB 32
#define CCH 384

__device__ __forceinline__ float leaky(float x) { return fmaxf(x, 0.1f * x); }

typedef _Float16 f16x8 __attribute__((ext_vector_type(8)));
typedef float f32x4 __attribute__((ext_vector_type(4)));

union F8 { uint4 q; f16x8 h; };
union H2 { _Float16 f[2]; uint32_t u; };

__device__ __forceinline__ void split2(float d0, float d1,
                                       uint32_t& hw, uint32_t& lw) {
  H2 h, l;
  h.f[0] = (_Float16)d0; h.f[1] = (_Float16)d1;
  l.f[0] = (_Float16)((d0 - (float)h.f[0]) * 2048.0f);
  l.f[1] = (_Float16)((d1 - (float)h.f[1]) * 2048.0f);
  hw = h.u; lw = l.u;
}

// ---------------------------------------------------------------- conv ------
// R17 verbatim. grid 352: bx<128 win1 64-row tiles; 128..255 win3 32-row
// tiles; 256..351 wsplit for w1..w3.
__global__ __launch_bounds__(256) void conv_kernel(
    const float* __restrict__ x, const float* __restrict__ mask,
    const float* __restrict__ cw0, const float* __restrict__ cw1,
    const float* __restrict__ w1, const float* __restrict__ w2,
    const float* __restrict__ w3,
    float* __restrict__ yG, float* __restrict__ Ssum, float* __restrict__ Ssq,
    uint32_t* __restrict__ wpk)
{
  int bx = blockIdx.x;
  int tid = threadIdx.x;
  if (bx >= 256) {                        // ---- wsplit
    int e = (bx - 256) * 256 + tid;
    int L = e >> 13;
    int r = e & 8191;
    int k2 = r >> 7, n = r & 127;
    int k = k2 * 2;
    const float* w = (L == 0) ? w1 : (L == 1) ? w2 : w3;
    uint32_t hw, lw;
    split2(w[k * 128 + n], w[(k + 1) * 128 + n], hw, lw);
    wpk[L * 8192 + n * 64 + k2] = hw;
    wpk[24576 + L * 8192 + n * 64 + k2] = lw;
    return;
  }

  __shared__ uint32_t Ah[64 * 68], Al[64 * 68];
  __shared__ uint32_t Bh[64 * 68], Bl[64 * 68];

  int wid = __builtin_amdgcn_readfirstlane(tid >> 6);
  int lane = tid & 63;
  int m16 = lane & 15, q = lane >> 4;

  if (bx < 128) {
    // win1: 64-row tiles, K=512, waves 2m x 2n
    int nb = bx & 3, mb = bx >> 2;
    int n0 = nb * 64;
    int row0 = mb * 64;
    const float* wbase = cw0 + n0 * 512;
    int wm = wid & 1, wn2 = wid >> 1;

    f32x4 hi[2][2], cr[2][2];
#pragma unroll
    for (int a = 0; a < 2; ++a)
#pragma unroll
      for (int b = 0; b < 2; ++b) {
        hi[a][b] = (f32x4){0.f, 0.f, 0.f, 0.f};
        cr[a][b] = (f32x4){0.f, 0.f, 0.f, 0.f};
      }

#pragma unroll 1
    for (int ch = 0; ch < 4; ++ch) {
      int kg0 = ch * 128;
      __syncthreads();
#pragma unroll 1
      for (int it = 0; it < 4; ++it) {
        int idx = it * 256 + tid;
        int r = idx >> 4;
        int k8 = (idx & 15) * 8;
        float d[8];
        int rowg = row0 + r;
        {
          float mv = mask[rowg];
          const float* xp = x + rowg * 512 + kg0 + k8;
          float4 a0 = *(const float4*)xp;
          float4 a1 = *(const float4*)(xp + 4);
          d[0] = a0.x * mv; d[1] = a0.y * mv; d[2] = a0.z * mv; d[3] = a0.w * mv;
          d[4] = a1.x * mv; d[5] = a1.y * mv; d[6] = a1.z * mv; d[7] = a1.w * mv;
        }
        uint4 hq, lq;
        split2(d[0], d[1], hq.x, lq.x);
        split2(d[2], d[3], hq.y, lq.y);
        split2(d[4], d[5], hq.z, lq.z);
        split2(d[6], d[7], hq.w, lq.w);
        *(uint4*)&Ah[r * 68 + k8 / 2] = hq;
        *(uint4*)&Al[r * 68 + k8 / 2] = lq;
        const float* wp = wbase + r * 512 + kg0 + k8;
        float4 b0v = *(const float4*)wp;
        float4 b1v = *(const float4*)(wp + 4);
        split2(b0v.x, b0v.y, hq.x, lq.x);
        split2(b0v.z, b0v.w, hq.y, lq.y);
        split2(b1v.x, b1v.y, hq.z, lq.z);
        split2(b1v.z, b1v.w, hq.w, lq.w);
        *(uint4*)&Bh[r * 68 + k8 / 2] = hq;
        *(uint4*)&Bl[r * 68 + k8 / 2] = lq;
      }
      __syncthreads();
#pragma unroll
      for (int ks = 0; ks < 4; ++ks) {
        int koff = ks * 16 + q * 4;
        F8 bh[2], bl[2];
#pragma unroll
        for (int nt = 0; nt < 2; ++nt) {
          int br = wn2 * 32 + nt * 16 + m16;
          bh[nt].q = *(const uint4*)&Bh[br * 68 + koff];
          bl[nt].q = *(const uint4*)&Bl[br * 68 + koff];
        }
#pragma unroll
        for (int mt = 0; mt < 2; ++mt) {
          int ar = wm * 32 + mt * 16 + m16;
          F8 ah, al;
          ah.q = *(const uint4*)&Ah[ar * 68 + koff];
          al.q = *(const uint4*)&Al[ar * 68 + koff];
#pragma unroll
          for (int nt = 0; nt < 2; ++nt) {
            hi[mt][nt] = __builtin_amdgcn_mfma_f32_16x16x32_f16(
                ah.h, bh[nt].h, hi[mt][nt], 0, 0, 0);
            cr[mt][nt] = __builtin_amdgcn_mfma_f32_16x16x32_f16(
                ah.h, bl[nt].h, cr[mt][nt], 0, 0, 0);
            cr[mt][nt] = __builtin_amdgcn_mfma_f32_16x16x32_f16(
                al.h, bh[nt].h, cr[mt][nt], 0, 0, 0);
          }
        }
      }
    }

    float y[2][2][4];
#pragma unroll
    for (int mt = 0; mt < 2; ++mt)
#pragma unroll
      for (int nt = 0; nt < 2; ++nt)
#pragma unroll
        for (int rg = 0; rg < 4; ++rg)
          y[mt][nt][rg] = hi[mt][nt][rg] + cr[mt][nt][rg] * (1.0f / 2048.0f);

#pragma unroll
    for (int nt = 0; nt < 2; ++nt) {
      float s = 0.f, s2 = 0.f;
#pragma unroll
      for (int mt = 0; mt < 2; ++mt)
#pragma unroll
        for (int rg = 0; rg < 4; ++rg) {
          float v = y[mt][nt][rg];
          s += v; s2 += v * v;
        }
      s  += __shfl_xor(s, 16, 64);  s  += __shfl_xor(s, 32, 64);
      s2 += __shfl_xor(s2, 16, 64); s2 += __shfl_xor(s2, 32, 64);
      if (lane < 16) {
        int c = n0 + wn2 * 32 + nt * 16 + m16;
        atomicAdd(&Ssum[c], s);
        atomicAdd(&Ssq[c], s2);
      }
    }

    __syncthreads();
    float* Yl = (float*)Ah;
#pragma unroll
    for (int mt = 0; mt < 2; ++mt)
#pragma unroll
      for (int nt = 0; nt < 2; ++nt)
#pragma unroll
        for (int rg = 0; rg < 4; ++rg)
          Yl[(wn2 * 32 + nt * 16 + m16) * 68 + wm * 32 + mt * 16 + q * 4 + rg] =
              y[mt][nt][rg];
    __syncthreads();
    {
      int c = tid >> 2, seg = (tid & 3) * 16;
#pragma unroll
      for (int j = 0; j < 16; j += 4)
        *(float4*)&yG[(n0 + c) * 2048 + row0 + seg + j] =
            *(const float4*)&Yl[c * 68 + seg + j];
    }
    return;
  }

  // win3: 32-row tiles, K=1536, waves 1m x 4n
  {
    int t = bx - 128;
    int nb3 = t & 1, mb3 = t >> 1;
    int n0 = 256 + nb3 * 64;
    int row0 = mb3 * 32;
    const float* wbase = cw1 + (n0 - 256) * 1536;

    f32x4 hi3[2], cr3[2];
#pragma unroll
    for (int mt = 0; mt < 2; ++mt) {
      hi3[mt] = (f32x4){0.f, 0.f, 0.f, 0.f};
      cr3[mt] = (f32x4){0.f, 0.f, 0.f, 0.f};
    }

#pragma unroll 1
    for (int ch = 0; ch < 12; ++ch) {
      int kg0 = ch * 128;
      int tap = kg0 >> 9;
      int d0 = kg0 & 511;
      int shift = (tap - 1) * 32;
      __syncthreads();
#pragma unroll 1
      for (int it = 0; it < 6; ++it) {
        int idx = it * 256 + tid;
        if (idx < 512) {
          int r = idx >> 4;
          int k8 = (idx & 15) * 8;
          float d[8];
          int rowg = row0 + r + shift;
          if ((unsigned)rowg < 2048u) {
            float mv = mask[rowg];
            const float* xp = x + rowg * 512 + d0 + k8;
            float4 a0 = *(const float4*)xp;
            float4 a1 = *(const float4*)(xp + 4);
            d[0] = a0.x * mv; d[1] = a0.y * mv; d[2] = a0.z * mv; d[3] = a0.w * mv;
            d[4] = a1.x * mv; d[5] = a1.y * mv; d[6] = a1.z * mv; d[7] = a1.w * mv;
          } else {
#pragma unroll
            for (int t2 = 0; t2 < 8; ++t2) d[t2] = 0.f;
          }
          uint4 hq, lq;
          split2(d[0], d[1], hq.x, lq.x);
          split2(d[2], d[3], hq.y, lq.y);
          split2(d[4], d[5], hq.z, lq.z);
          split2(d[6], d[7], hq.w, lq.w);
          *(uint4*)&Ah[r * 68 + k8 / 2] = hq;
          *(uint4*)&Al[r * 68 + k8 / 2] = lq;
        } else {
          int idx2 = idx - 512;
          int r = idx2 >> 4;
          int k8 = (idx2 & 15) * 8;
          const float* wp = wbase + r * 1536 + kg0 + k8;
          float4 b0v = *(const float4*)wp;
          float4 b1v = *(const float4*)(wp + 4);
          uint4 hq, lq;
          split2(b0v.x, b0v.y, hq.x, lq.x);
          split2(b0v.z, b0v.w, hq.y, lq.y);
          split2(b1v.x, b1v.y, hq.z, lq.z);
          split2(b1v.z, b1v.w, hq.w, lq.w);
          *(uint4*)&Bh[r * 68 + k8 / 2] = hq;
          *(uint4*)&Bl[r * 68 + k8 / 2] = lq;
        }
      }
      __syncthreads();
#pragma unroll
      for (int ks = 0; ks < 4; ++ks) {
        int koff = ks * 16 + q * 4;
        F8 bh, bl;
        int br = wid * 16 + m16;
        bh.q = *(const uint4*)&Bh[br * 68 + koff];
        bl.q = *(const uint4*)&Bl[br * 68 + koff];
#pragma unroll
        for (int mt = 0; mt < 2; ++mt) {
          int ar = mt * 16 + m16;
          F8 ah, al;
          ah.q = *(const uint4*)&Ah[ar * 68 + koff];
          al.q = *(const uint4*)&Al[ar * 68 + koff];
          hi3[mt] = __builtin_amdgcn_mfma_f32_16x16x32_f16(
              ah.h, bh.h, hi3[mt], 0, 0, 0);
          cr3[mt] = __builtin_amdgcn_mfma_f32_16x16x32_f16(
              ah.h, bl.h, cr3[mt], 0, 0, 0);
          cr3[mt] = __builtin_amdgcn_mfma_f32_16x16x32_f16(
              al.h, bh.h, cr3[mt], 0, 0, 0);
        }
      }
    }

    float y3[2][4];
#pragma unroll
    for (int mt = 0; mt < 2; ++mt)
#pragma unroll
      for (int rg = 0; rg < 4; ++rg)
        y3[mt][rg] = hi3[mt][rg] + cr3[mt][rg] * (1.0f / 2048.0f);

    {
      float s = 0.f, s2 = 0.f;
#pragma unroll
      for (int mt = 0; mt < 2; ++mt)
#pragma unroll
        for (int rg = 0; rg < 4; ++rg) {
          float v = y3[mt][rg];
          s += v; s2 += v * v;
        }
      s  += __shfl_xor(s, 16, 64);  s  += __shfl_xor(s, 32, 64);
      s2 += __shfl_xor(s2, 16, 64); s2 += __shfl_xor(s2, 32, 64);
      if (lane < 16) {
        int c = n0 + wid * 16 + m16;
        atomicAdd(&Ssum[c], s);
        atomicAdd(&Ssq[c], s2);
      }
    }

    __syncthreads();
    float* Yl = (float*)Ah;
#pragma unroll
    for (int mt = 0; mt < 2; ++mt)
#pragma unroll
      for (int rg = 0; rg < 4; ++rg)
        Yl[(wid * 16 + m16) * 34 + mt * 16 + q * 4 + rg] = y3[mt][rg];
    __syncthreads();
    {
      int c = tid >> 2, seg = (tid & 3) * 8;
#pragma unroll
      for (int j = 0; j < 8; j += 4)
        *(float4*)&yG[(n0 + c) * 2048 + row0 + seg + j] =
            *(const float4*)&Yl[c * 34 + seg + j];
    }
  }
}

// ------------------------------------------------------------------ ab ------
// R17 verbatim. grid 512: 16-row x 64-col tiles, K staged 6 x 64.
__global__ __launch_bounds__(256) void ab_kernel(
    const float* __restrict__ yG, const float* __restrict__ Ssum,
    const float* __restrict__ Ssq,
    const float* __restrict__ g0, const float* __restrict__ be0,
    const float* __restrict__ g1, const float* __restrict__ be1,
    const float* __restrict__ mask, const float* __restrict__ w0,
    float* __restrict__ a_arr, float* __restrict__ bb_arr)
{
  int bx = blockIdx.x;
  int tid = threadIdx.x;
  __shared__ float As[64 * 20];
  __shared__ float Ws[64 * 68];
  __shared__ float scs[384], shs[384];
  for (int c = tid; c < 384; c += 256) {
    float Sv = Ssum[c], S2v = Ssq[c];
    float mean = Sv * (1.f / 2048.f);
    float var  = S2v * (1.f / 2048.f) - mean * mean;
    float g  = (c < 256) ? g0[c] : g1[c - 256];
    float be = (c < 256) ? be0[c] : be1[c - 256];
    float sc = g / sqrtf(var + 1e-5f);
    scs[c] = sc;
    shs[c] = be - mean * sc;
  }
  __syncthreads();

  int rt = bx >> 2, ct = bx & 3;
  int row0 = rt * 16, n0 = ct * 64;
  int cth = tid >> 2;
  int srr4 = (tid & 3) * 4;
  int wn16 = (tid & 3) * 16;
  int r4 = (tid >> 6) * 4;
  int n1 = tid & 63;
  const float* wbase = (n0 < 128) ? (w0 + n0) : (w0 + CCH * 128 + (n0 - 128));
  float4 mv = *(const float4*)(mask + row0 + srr4);

  float acc[4] = {0.f, 0.f, 0.f, 0.f};
#pragma unroll 1
  for (int c0 = 0; c0 < 384; c0 += 64) {
    int c = c0 + cth;
    float4 yv = *(const float4*)(yG + c * 2048 + row0 + srr4);
    float sc = scs[c], sh = shs[c];
    float4 wv0 = *(const float4*)(wbase + c * 128 + wn16);
    float4 wv1 = *(const float4*)(wbase + c * 128 + wn16 + 4);
    float4 wv2 = *(const float4*)(wbase + c * 128 + wn16 + 8);
    float4 wv3 = *(const float4*)(wbase + c * 128 + wn16 + 12);
    __syncthreads();
    float4 hv;
    hv.x = leaky(fmaf(yv.x, sc, sh)) * mv.x;
    hv.y = leaky(fmaf(yv.y, sc, sh)) * mv.y;
    hv.z = leaky(fmaf(yv.z, sc, sh)) * mv.z;
    hv.w = leaky(fmaf(yv.w, sc, sh)) * mv.w;
    *(float4*)&As[cth * 20 + srr4] = hv;
    *(float4*)&Ws[cth * 68 + wn16]      = wv0;
    *(float4*)&Ws[cth * 68 + wn16 + 4]  = wv1;
    *(float4*)&Ws[cth * 68 + wn16 + 8]  = wv2;
    *(float4*)&Ws[cth * 68 + wn16 + 12] = wv3;
    __syncthreads();
#pragma unroll 16
    for (int cc = 0; cc < 64; ++cc) {
      float4 a = *(const float4*)&As[cc * 20 + r4];
      float w  = Ws[cc * 68 + n1];
      acc[0] = fmaf(a.x, w, acc[0]);
      acc[1] = fmaf(a.y, w, acc[1]);
      acc[2] = fmaf(a.z, w, acc[2]);
      acc[3] = fmaf(a.w, w, acc[3]);
    }
  }
  float* dst; int nd;
  if (n0 < 128) { dst = a_arr; nd = n0; } else { dst = bb_arr; nd = n0 - 128; }
#pragma unroll
  for (int ri = 0; ri < 4; ++ri)
    dst[(row0 + r4 + ri) * 128 + nd + n1] = acc[ri];
}

// ---------------------------------------------------------------- pair ------
// R18: grid (64,4) = 1 block/CU; each block runs 8 b-iterations with
// double-buffered A staging (issue-early/write-late) and writes p rows
// to p_arr. Epilogue moved to out_kernel.
__global__ __launch_bounds__(512) void pair_kernel(
    const float* __restrict__ a_arr, const float* __restrict__ bb_arr,
    const float* __restrict__ b0, const uint32_t* __restrict__ wpk,
    const float* __restrict__ b1, const float* __restrict__ b2,
    const float* __restrict__ b3, const float* __restrict__ mask,
    float* __restrict__ p_arr)
{
  __shared__ uint32_t AhsD[2][64 * 68];
  __shared__ uint32_t AlsD[2][64 * 68];
  __shared__ float Pm[128];
  int i = blockIdx.x, bp = blockIdx.y;
  int tid = threadIdx.x;
  int wid = __builtin_amdgcn_readfirstlane(tid >> 6);
  int lane = tid & 63;
  int m16 = lane & 15, q = lane >> 4;
  int wn16 = wid * 16, wrow = wn16 + m16;
  int k8 = (tid & 15) * 8;
  int r0 = tid >> 4;                      // 0..31

  // (L0, ks0) weight frags: issued first, hide under prologue staging
  F8 Wh, Wl, Whn, Wln;
  Wh.q = *(const uint4*)(wpk + wrow * 64 + q * 4);
  Wl.q = *(const uint4*)(wpk + 24576 + wrow * 64 + q * 4);

  float zz[8];
  *(float4*)&zz[0] = *(const float4*)(b0 + k8);
  *(float4*)&zz[4] = *(const float4*)(b0 + k8 + 4);

  int bbase = bp * 8;
  int brow0 = i * BB + bbase;

  float av[8], bv[2][8];
  auto LOADB = [&](int bt) {
    const float* ap = a_arr + (i * BB + bt) * 128 + k8;
    *(float4*)&av[0] = *(const float4*)ap;
    *(float4*)&av[4] = *(const float4*)(ap + 4);
#pragma unroll
    for (int it = 0; it < 2; ++it) {
      int r = it * 32 + r0;
      const float* bbp = bb_arr + (r * BB + bt) * 128 + k8;
      *(float4*)&bv[it][0] = *(const float4*)bbp;
      *(float4*)&bv[it][4] = *(const float4*)(bbp + 4);
    }
  };
  auto WRITEB = [&](int buf) {
    uint32_t* Ah = AhsD[buf];
    uint32_t* Al = AlsD[buf];
#pragma unroll
    for (int it = 0; it < 2; ++it) {
      int r = it * 32 + r0;
      float d[8];
#pragma unroll
      for (int j = 0; j < 8; ++j) d[j] = leaky(av[j] + zz[j] + bv[it][j]);
      uint4 hq, lq;
      split2(d[0], d[1], hq.x, lq.x);
      split2(d[2], d[3], hq.y, lq.y);
      split2(d[4], d[5], hq.z, lq.z);
      split2(d[6], d[7], hq.w, lq.w);
      *(uint4*)&Ah[r * 68 + k8 / 2] = hq;
      *(uint4*)&Al[r * 68 + k8 / 2] = lq;
    }
  };

  LOADB(bbase);
  WRITEB(0);
  __syncthreads();

  f32x4 hi[4], cr[4];

#pragma unroll 1
  for (int t = 0; t < 8; ++t) {
    int browp = brow0 + t;
    if (t < 7) LOADB(bbase + t + 1);      // issue-early: lands during L0 MFMA
    int cur = t & 1;
    uint32_t* Ahs = AhsD[cur];
    uint32_t* Als = AlsD[cur];

#pragma unroll 1
    for (int L = 0; L < 3; ++L) {
      const uint32_t* WhL = wpk + L * 8192;
      const uint32_t* WlL = wpk + 24576 + L * 8192;
      const float* Bv = (L == 0) ? b1 : (L == 1) ? b2 : b3;
#pragma unroll
      for (int mt = 0; mt < 4; ++mt) {
        hi[mt] = (f32x4){0.f, 0.f, 0.f, 0.f};
        cr[mt] = (f32x4){0.f, 0.f, 0.f, 0.f};
      }

#pragma unroll
      for (int ks = 0; ks < 4; ++ks) {
        int koff = ks * 16 + q * 4;
        if (ks < 3) {
          Whn.q = *(const uint4*)(WhL + wrow * 64 + koff + 16);
          Wln.q = *(const uint4*)(WlL + wrow * 64 + koff + 16);
        } else {
          // wrap: next layer, or L0 for the next b-iteration
          const uint32_t* nh = (L < 2) ? (WhL + 8192) : wpk;
          const uint32_t* nl = (L < 2) ? (WlL + 8192) : (wpk + 24576);
          Whn.q = *(const uint4*)(nh + wrow * 64 + q * 4);
          Wln.q = *(const uint4*)(nl + wrow * 64 + q * 4);
        }
#pragma unroll
        for (int mt = 0; mt < 4; ++mt) {
          int arow = mt * 16 + m16;
          F8 Ah, Al;
          Ah.q = *(const uint4*)&Ahs[arow * 68 + koff];
          Al.q = *(const uint4*)&Als[arow * 68 + koff];
          hi[mt] = __builtin_amdgcn_mfma_f32_16x16x32_f16(
              Ah.h, Wh.h, hi[mt], 0, 0, 0);
          cr[mt] = __builtin_amdgcn_mfma_f32_16x16x32_f16(
              Ah.h, Wl.h, cr[mt], 0, 0, 0);
          cr[mt] = __builtin_amdgcn_mfma_f32_16x16x32_f16(
              Al.h, Wh.h, cr[mt], 0, 0, 0);
        }
        Wh = Whn; Wl = Wln;
      }

      float bias = Bv[wrow];

      if (L < 2) {
        __syncthreads();
        int par = lane & 1;
        int colw = (wn16 + (m16 & ~1)) >> 1;
#pragma unroll
        for (int mt = 0; mt < 4; ++mt) {
#pragma unroll
          for (int rg = 0; rg < 4; ++rg) {
            float dd = leaky(hi[mt][rg] + cr[mt][rg] * (1.0f / 2048.0f) + bias);
            float dn = __shfl_xor(dd, 1, 64);
            float de = par ? dn : dd;
            float do_ = par ? dd : dn;
            uint32_t hw, lw;
            split2(de, do_, hw, lw);
            int row = mt * 16 + q * 4 + rg;
            if (par) Als[row * 68 + colw] = lw;
            else     Ahs[row * 68 + colw] = hw;
          }
        }
        __syncthreads();
        if (L == 0 && t < 7) WRITEB(cur ^ 1);   // write-late: staged b+1
      } else {
        float s = 0.f;
#pragma unroll
        for (int mt = 0; mt < 4; ++mt)
#pragma unroll
          for (int rg = 0; rg < 4; ++rg)
            s += leaky(hi[mt][rg] + cr[mt][rg] * (1.0f / 2048.0f) + bias);
        s += __shfl_xor(s, 16, 64);
        s += __shfl_xor(s, 32, 64);
        float mfac = (1.0f / 64.0f) * mask[browp];
        __syncthreads();                       // prior Pm consumed; L2 reads done
        if (lane < 16) Pm[wrow] = s * mfac;
        __syncthreads();
        if (tid < 128) p_arr[browp * 128 + tid] = Pm[tid];
      }
    }
  }
}

// ----------------------------------------------------------------- out ------
// grid 256 x 256 thr: 8 rows/block. T = leaky(p@w4+b4); out = leaky(T@w5+b5)
// * mask. w4/w5 read once per block (L2-hot), coalesced.
__global__ __launch_bounds__(256) void out_kernel(
    const float* __restrict__ p_arr,
    const float* __restrict__ w4, const float* __restrict__ b4,
    const float* __restrict__ w5, const float* __restrict__ b5,
    const float* __restrict__ mask, float* __restrict__ out)
{
  __shared__ float Ps[8 * 128];
  __shared__ float Ts[8 * 128];
  int bx = blockIdx.x;
  int tid = threadIdx.x;
  int row0 = bx * 8;

  // stage p rows (coalesced)
  {
    int o = tid * 4;
    *(float4*)&Ps[o] = *(const float4*)(p_arr + row0 * 128 + o);
  }
  __syncthreads();

  // T = leaky(P @ w4 + b4): 1024 outputs, 4 per thread (same row)
  {
    int o = tid * 4;
    int rr = o >> 7, cc = o & 127;
    float4 acc = *(const float4*)(b4 + cc);
    const float* pr = Ps + rr * 128;
#pragma unroll 8
    for (int c = 0; c < 128; ++c) {
      float pv = pr[c];
      float4 wv = *(const float4*)(w4 + c * 128 + cc);
      acc.x = fmaf(pv, wv.x, acc.x);
      acc.y = fmaf(pv, wv.y, acc.y);
      acc.z = fmaf(pv, wv.z, acc.z);
      acc.w = fmaf(pv, wv.w, acc.w);
    }
    float4 tv;
    tv.x = leaky(acc.x); tv.y = leaky(acc.y);
    tv.z = leaky(acc.z); tv.w = leaky(acc.w);
    *(float4*)&Ts[o] = tv;
  }
  __syncthreads();

  // out = leaky(T @ w5 + b5) * mask: thread owns 2 cols x 8 rows
  {
    int kk = tid * 2;
    float acc[8][2];
    float b5v0 = b5[kk], b5v1 = b5[kk + 1];
#pragma unroll
    for (int r = 0; r < 8; ++r) { acc[r][0] = b5v0; acc[r][1] = b5v1; }
#pragma unroll 4
    for (int c = 0; c < 128; ++c) {
      float2 wv = *(const float2*)(w5 + c * 512 + kk);
#pragma unroll
      for (int r = 0; r < 8; ++r) {
        float tv = Ts[r * 128 + c];
        acc[r][0] = fmaf(tv, wv.x, acc[r][0]);
        acc[r][1] = fmaf(tv, wv.y, acc[r][1]);
      }
    }
#pragma unroll
    for (int r = 0; r < 8; ++r) {
      float mk = mask[row0 + r];
      float2 ov;
      ov.x = leaky(acc[r][0]) * mk;
      ov.y = leaky(acc[r][1]) * mk;
      *(float2*)&out[(row0 + r) * 512 + kk] = ov;
    }
  }
}

// -------------------------------------------------------------- launch ------
extern "C" void kernel_launch(void* const* d_in, const int* in_sizes, int n_in,
                              void* d_out, int out_size, void* d_ws, size_t ws_size,
                              hipStream_t stream) {
  const float* x    = (const float*)d_in[0];
  const float* mask = (const float*)d_in[1];
  const float* cw0  = (const float*)d_in[2];
  // d_in[3] conv_b0: cancels in BN
  const float* g0   = (const float*)d_in[4];
  const float* be0  = (const float*)d_in[5];
  const float* cw1  = (const float*)d_in[6];
  // d_in[7] conv_b1: cancels in BN
  const float* g1   = (const float*)d_in[8];
  const float* be1  = (const float*)d_in[9];
  const float* w0   = (const float*)d_in[10];
  const float* b0   = (const float*)d_in[11];
  const float* w1   = (const float*)d_in[12];
  const float* b1   = (const float*)d_in[13];
  const float* w2   = (const float*)d_in[14];
  const float* b2   = (const float*)d_in[15];
  const float* w3   = (const float*)d_in[16];
  const float* b3   = (const float*)d_in[17];
  const float* w4   = (const float*)d_in[18];
  const float* b4   = (const float*)d_in[19];
  const float* w5   = (const float*)d_in[20];
  const float* b5   = (const float*)d_in[21];

  float* ws     = (float*)d_ws;
  float* Ssum   = ws;                         // 384
  float* Ssq    = ws + 384;                   // 384
  float* yG     = ws + 768;                   // 384*2048 = 786432
  uint32_t* wpk = (uint32_t*)(ws + 787200);   // 49152
  float* a_arr  = ws + 836352;                // 2048*128
  float* bb_arr = ws + 1098496;               // 2048*128
  float* p_arr  = yG;                         // yG dead after ab -> reuse
  float* outp   = (float*)d_out;

  hipMemsetAsync(Ssum, 0, 768 * sizeof(float), stream);
  conv_kernel<<<352, 256, 0, stream>>>(x, mask, cw0, cw1, w1, w2, w3,
                                       yG, Ssum, Ssq, wpk);
  ab_kernel<<<512, 256, 0, stream>>>(yG, Ssum, Ssq, g0, be0, g1, be1,
                                     mask, w0, a_arr, bb_arr);
  dim3 g5(64, 4);
  pair_kernel<<<g5, 512, 0, stream>>>(a_arr, bb_arr, b0, wpk, b1, b2, b3,
                                      mask, p_arr);
  out_kernel<<<256, 256, 0, stream>>>(p_arr, w4, b4, w5, b5, mask, outp);
}